// Round 24
// baseline (122.840 us; speedup 1.0000x reference)
//
#include <hip/hip_runtime.h>
#include <math.h>

// ManifoldHyperConnectionFuse on MI355X — R23: TWO-KERNEL SPLIT (+ablation).
// R19-R22: occupancy 36-74%, FETCH 66-125MB, VALU 24-42%, barriers 3-0 all
// moved; dur pinned 76-82us -> the fused wave's serial stage|A|scalar|C
// chain can't saturate anything. Split at the natural seam:
//   kernel A: matvec+Sinkhorn -> 24 "smalls"/token, stashed in the first
//             24 floats of each token's own d_out row (kernel B reads them
//             before overwriting the row; same-wave program order = safe).
//             No LDS tile -> occupancy uncapped. = R21's proven phase A.
//   kernel B: pure streaming phase C, grid-stride, h is L3-hot.
// rocprof now shows each phase separately — the ablation I've never had.

typedef __attribute__((ext_vector_type(2))) _Float16 h2v;

__device__ __forceinline__ float fdot2f(unsigned int a, unsigned int b, float c) {
#if __has_builtin(__builtin_amdgcn_fdot2)
    return __builtin_amdgcn_fdot2(__builtin_bit_cast(h2v, a),
                                  __builtin_bit_cast(h2v, b), c, false);
#else
    h2v av = __builtin_bit_cast(h2v, a);
    h2v bv = __builtin_bit_cast(h2v, b);
    return fmaf((float)av[1], (float)bv[1],
           fmaf((float)av[0], (float)bv[0], c));
#endif
}

__device__ __forceinline__ unsigned int pk_f16(float a, float b) {
    const auto p = __builtin_amdgcn_cvt_pkrtz(a, b);   // __fp16x2
    return __builtin_bit_cast(unsigned int, p);
}

__device__ __forceinline__ float sigmoid_f(float z) {
    return 1.0f / (1.0f + __expf(-z));
}

__device__ __forceinline__ void wave_lds_fence() {
    asm volatile("s_waitcnt lgkmcnt(0)" ::: "memory");
    __builtin_amdgcn_sched_barrier(0);
}

// sum over each aligned 16-lane row via DPP row_ror (VALU-only)
__device__ __forceinline__ float row16_sum(float x) {
    x += __int_as_float(__builtin_amdgcn_update_dpp(
        0, __float_as_int(x), 0x121, 0xf, 0xf, false)); // row_ror:1
    x += __int_as_float(__builtin_amdgcn_update_dpp(
        0, __float_as_int(x), 0x122, 0xf, 0xf, false)); // row_ror:2
    x += __int_as_float(__builtin_amdgcn_update_dpp(
        0, __float_as_int(x), 0x124, 0xf, 0xf, false)); // row_ror:4
    x += __int_as_float(__builtin_amdgcn_update_dpp(
        0, __float_as_int(x), 0x128, 0xf, 0xf, false)); // row_ror:8
    return x;
}

// ---- prep: fold alpha*nw*w -> f16 wt[24][1024] (n-major) in d_ws ----
__global__ __launch_bounds__(256)
void prep_kernel(const float* __restrict__ nw,
                 const float* __restrict__ w,
                 const float* __restrict__ alpha,
                 unsigned short* __restrict__ wt)
{
    const int tid = blockIdx.x * 256 + threadIdx.x;   // 6144 threads
    const int flat = 4 * tid;                          // w is [k][n], flat=k*24+n
    const float4 w4 = *(const float4*)(w + flat);
    const float a0 = alpha[0], a1 = alpha[1], a2 = alpha[2];
    const float vals[4] = {w4.x, w4.y, w4.z, w4.w};
    #pragma unroll
    for (int c = 0; c < 4; ++c) {
        const int f = flat + c;
        const int k = f / 24;
        const int n = f - 24 * k;
        const float as = (n < 4) ? a0 : ((n < 8) ? a1 : a2);
        const unsigned int p = pk_f16(as * nw[k] * vals[c], 0.f);
        wt[n * 1024 + k] = (unsigned short)(p & 0xffffu);
    }
}

// ---- kernel A: matvec + Sinkhorn -> smalls stash (24 floats/token) ----
__global__ __launch_bounds__(256)
void phaseA_kernel(const float* __restrict__ h,
                   const unsigned short* __restrict__ wt,
                   const float* __restrict__ beta,
                   float* __restrict__ out)   // only stash regions written
{
    const int tid  = threadIdx.x;
    const int lane = tid & 63;
    const int wv   = tid >> 6;     // wave owns tokens [4wv, 4wv+4)
    const int ksl  = lane & 15;
    const int ng   = lane >> 4;

    __shared__ float Hpart[16][28];   // wave-private rows

    const long tok0 = (long)blockIdx.x * 16;
    const int t0 = 4 * wv;
    const float* ph = h + (tok0 + t0) * 1024 + 4 * ksl;         // L3/HBM
    const uint2* twp = (const uint2*)wt + (6 * ng) * 256 + ksl; // L2-hot

    float acc[4][6], r2[4];
    #pragma unroll
    for (int t = 0; t < 4; ++t) {
        r2[t] = 0.f;
        #pragma unroll
        for (int j = 0; j < 6; ++j) acc[t][j] = 0.f;
    }

    #pragma unroll 1
    for (int e = 0; e < 16; ++e) {
        float4 xf[4];
        #pragma unroll
        for (int t = 0; t < 4; ++t)
            xf[t] = *(const float4*)(ph + t * 1024 + 64 * e);  // 256B segments
        uint2 wr[6];
        #pragma unroll
        for (int j = 0; j < 6; ++j) wr[j] = twp[j * 256 + e * 16];

        uint2 xw[4];
        #pragma unroll
        for (int t = 0; t < 4; ++t) {
            xw[t].x = pk_f16(xf[t].x, xf[t].y);
            xw[t].y = pk_f16(xf[t].z, xf[t].w);
        }

        #pragma unroll
        for (int j = 0; j < 6; ++j) {
            #pragma unroll
            for (int t = 0; t < 4; ++t) {
                acc[t][j] = fdot2f(xw[t].y, wr[j].y,
                            fdot2f(xw[t].x, wr[j].x, acc[t][j]));
            }
        }
        #pragma unroll
        for (int t = 0; t < 4; ++t) {      // r2 fp32-exact
            r2[t] = fmaf(xf[t].w, xf[t].w, fmaf(xf[t].z, xf[t].z,
                    fmaf(xf[t].y, xf[t].y, fmaf(xf[t].x, xf[t].x, r2[t]))));
        }
    }

    #pragma unroll
    for (int t = 0; t < 4; ++t) {
        #pragma unroll
        for (int j = 0; j < 6; ++j) acc[t][j] = row16_sum(acc[t][j]);
        r2[t] = row16_sum(r2[t]);
    }
    if (ksl == 0) {
        #pragma unroll
        for (int t = 0; t < 4; ++t) {
            #pragma unroll
            for (int j = 0; j < 6; ++j)
                Hpart[t0 + t][6 * ng + j] = acc[t][j];
            if (ng == 0) Hpart[t0 + t][24] = r2[t];
        }
    }
    wave_lds_fence();   // wave-private rows ready

    // scalar phase on lanes 0..3 of this wave; stash 24 floats to out row
    if (lane < 4) {
        const int t = t0 + lane;
        float Hp[24];
        #pragma unroll
        for (int q = 0; q < 24; ++q) Hp[q] = Hpart[t][q];
        const float r2v = Hpart[t][24];
        const float r_ = 1.0f / (sqrtf(r2v) * 0.03125f + 1e-6f);

        float Hpre[4], Hpost[4], K[16];
        #pragma unroll
        for (int n = 0; n < 4; ++n)
            Hpre[n] = sigmoid_f(fmaf(r_, Hp[n], beta[n]));
        #pragma unroll
        for (int n = 0; n < 4; ++n)
            Hpost[n] = 2.0f * sigmoid_f(fmaf(r_, Hp[4 + n], beta[4 + n]));
        #pragma unroll
        for (int q = 0; q < 16; ++q)
            K[q] = __expf(fmaf(r_, Hp[8 + q], beta[8 + q]));

        float u0=1.f,u1=1.f,u2=1.f,u3=1.f;
        float v0=1.f,v1=1.f,v2=1.f,v3=1.f;
        for (int itr = 0; itr < 10; ++itr) {
            u0 = 1.0f/(K[0]*v0  + K[1]*v1  + K[2]*v2  + K[3]*v3  + 1e-8f);
            u1 = 1.0f/(K[4]*v0  + K[5]*v1  + K[6]*v2  + K[7]*v3  + 1e-8f);
            u2 = 1.0f/(K[8]*v0  + K[9]*v1  + K[10]*v2 + K[11]*v3 + 1e-8f);
            u3 = 1.0f/(K[12]*v0 + K[13]*v1 + K[14]*v2 + K[15]*v3 + 1e-8f);
            v0 = 1.0f/(K[0]*u0  + K[4]*u1  + K[8]*u2  + K[12]*u3 + 1e-8f);
            v1 = 1.0f/(K[1]*u0  + K[5]*u1  + K[9]*u2  + K[13]*u3 + 1e-8f);
            v2 = 1.0f/(K[2]*u0  + K[6]*u1  + K[10]*u2 + K[14]*u3 + 1e-8f);
            v3 = 1.0f/(K[3]*u0  + K[7]*u1  + K[11]*u2 + K[15]*u3 + 1e-8f);
        }
        float4 o0, o1, o2, o3, o4, o5;
        o0.x = Hpre[0];  o0.y = Hpre[1];  o0.z = Hpre[2];  o0.w = Hpre[3];
        o1.x = Hpost[0]; o1.y = Hpost[1]; o1.z = Hpost[2]; o1.w = Hpost[3];
        o2.x = u0*K[0]*v0;  o2.y = u0*K[1]*v1;  o2.z = u0*K[2]*v2;  o2.w = u0*K[3]*v3;
        o3.x = u1*K[4]*v0;  o3.y = u1*K[5]*v1;  o3.z = u1*K[6]*v2;  o3.w = u1*K[7]*v3;
        o4.x = u2*K[8]*v0;  o4.y = u2*K[9]*v1;  o4.z = u2*K[10]*v2; o4.w = u2*K[11]*v3;
        o5.x = u3*K[12]*v0; o5.y = u3*K[13]*v1; o5.z = u3*K[14]*v2; o5.w = u3*K[15]*v3;
        float* sp = out + (tok0 + t) * 1024;
        *(float4*)(sp + 0)  = o0;  *(float4*)(sp + 4)  = o1;
        *(float4*)(sp + 8)  = o2;  *(float4*)(sp + 12) = o3;
        *(float4*)(sp + 16) = o4;  *(float4*)(sp + 20) = o5;
    }
}

// ---- kernel B: streaming phase C. Reads stash from out row, overwrites it ----
__global__ __launch_bounds__(256)
void phaseC_kernel(const float* __restrict__ h,
                   float* out)     // NOT restrict: stash read aliases writes
{
    const int tid  = threadIdx.x;
    const int lane = tid & 63;
    const int wv   = tid >> 6;
    const long gw  = (long)blockIdx.x * 4 + wv;   // 8192 grid-waves

    #pragma unroll 2
    for (int i = 0; i < 4; ++i) {
        const long tok = gw * 4 + i;

        const float* sp = out + tok * 1024;       // stash (broadcast loads)
        const float4 s0  = *(const float4*)(sp + 0);   // Hpre
        const float4 s1  = *(const float4*)(sp + 4);   // Hpost
        const float4 q0  = *(const float4*)(sp + 8);   // P rows
        const float4 q1  = *(const float4*)(sp + 12);
        const float4 q2  = *(const float4*)(sp + 16);
        const float4 q3  = *(const float4*)(sp + 20);

        const float* pm = h + tok * 1024 + 4 * lane;   // L3-hot
        const float4 xm0 = *(const float4*)(pm);
        const float4 xm1 = *(const float4*)(pm + 256);
        const float4 xm2 = *(const float4*)(pm + 512);
        const float4 xm3 = *(const float4*)(pm + 768);

        float hpre[4];
        hpre[0] = s0.x*xm0.x + s0.y*xm1.x + s0.z*xm2.x + s0.w*xm3.x;
        hpre[1] = s0.x*xm0.y + s0.y*xm1.y + s0.z*xm2.y + s0.w*xm3.y;
        hpre[2] = s0.x*xm0.z + s0.y*xm1.z + s0.z*xm2.z + s0.w*xm3.z;
        hpre[3] = s0.x*xm0.w + s0.y*xm1.w + s0.z*xm2.w + s0.w*xm3.w;

        float* po = out + tok * 1024 + 4 * lane;
        float4 o;
        // n = 0
        o.x = fmaf(s1.x, hpre[0], q0.x*xm0.x + q0.y*xm1.x + q0.z*xm2.x + q0.w*xm3.x);
        o.y = fmaf(s1.x, hpre[1], q0.x*xm0.y + q0.y*xm1.y + q0.z*xm2.y + q0.w*xm3.y);
        o.z = fmaf(s1.x, hpre[2], q0.x*xm0.z + q0.y*xm1.z + q0.z*xm2.z + q0.w*xm3.z);
        o.w = fmaf(s1.x, hpre[3], q0.x*xm0.w + q0.y*xm1.w + q0.z*xm2.w + q0.w*xm3.w);
        *(float4*)(po) = o;
        // n = 1
        o.x = fmaf(s1.y, hpre[0], q1.x*xm0.x + q1.y*xm1.x + q1.z*xm2.x + q1.w*xm3.x);
        o.y = fmaf(s1.y, hpre[1], q1.x*xm0.y + q1.y*xm1.y + q1.z*xm2.y + q1.w*xm3.y);
        o.z = fmaf(s1.y, hpre[2], q1.x*xm0.z + q1.y*xm1.z + q1.z*xm2.z + q1.w*xm3.z);
        o.w = fmaf(s1.y, hpre[3], q1.x*xm0.w + q1.y*xm1.w + q1.z*xm2.w + q1.w*xm3.w);
        *(float4*)(po + 256) = o;
        // n = 2
        o.x = fmaf(s1.z, hpre[0], q2.x*xm0.x + q2.y*xm1.x + q2.z*xm2.x + q2.w*xm3.x);
        o.y = fmaf(s1.z, hpre[1], q2.x*xm0.y + q2.y*xm1.y + q2.z*xm2.y + q2.w*xm3.y);
        o.z = fmaf(s1.z, hpre[2], q2.x*xm0.z + q2.y*xm1.z + q2.z*xm2.z + q2.w*xm3.z);
        o.w = fmaf(s1.z, hpre[3], q2.x*xm0.w + q2.y*xm1.w + q2.z*xm2.w + q2.w*xm3.w);
        *(float4*)(po + 512) = o;
        // n = 3
        o.x = fmaf(s1.w, hpre[0], q3.x*xm0.x + q3.y*xm1.x + q3.z*xm2.x + q3.w*xm3.x);
        o.y = fmaf(s1.w, hpre[1], q3.x*xm0.y + q3.y*xm1.y + q3.z*xm2.y + q3.w*xm3.y);
        o.z = fmaf(s1.w, hpre[2], q3.x*xm0.z + q3.y*xm1.z + q3.z*xm2.z + q3.w*xm3.z);
        o.w = fmaf(s1.w, hpre[3], q3.x*xm0.w + q3.y*xm1.w + q3.z*xm2.w + q3.w*xm3.w);
        *(float4*)(po + 768) = o;
    }
}

extern "C" void kernel_launch(void* const* d_in, const int* in_sizes, int n_in,
                              void* d_out, int out_size, void* d_ws, size_t ws_size,
                              hipStream_t stream) {
    const float* h     = (const float*)d_in[0];
    const float* nw    = (const float*)d_in[1];
    const float* w     = (const float*)d_in[2];
    const float* alpha = (const float*)d_in[3];
    const float* beta  = (const float*)d_in[4];
    float* out = (float*)d_out;
    unsigned short* wt = (unsigned short*)d_ws;   // 24*1024*2B = 48KB

    prep_kernel<<<24, 256, 0, stream>>>(nw, w, alpha, wt);
    phaseA_kernel<<<2048, 256, 0, stream>>>(h, wt, beta, out);
    phaseC_kernel<<<2048, 256, 0, stream>>>(h, out);
}

// Round 25
// 67.876 us; speedup vs baseline: 1.8098x; 1.8098x over previous
//
#include <hip/hip_runtime.h>
#include <math.h>

// ManifoldHyperConnectionFuse on MI355X — R24: R19 + b128 loads (8 e-iters).
// R23 split-ablation: phaseA standalone ~= the whole fused kernel (phaseC
// hides completely under it); phaseA is latency-exposure-bound (VALU 35%,
// HBM 8%, occ 47%). The binder is the 16-iter serial e-loop: per-iter loads
// expose L2/L3 latency the compiler won't pipeline across the back-edge.
// R24 = R19 with ALL phase-A loads widened to 16B/lane (uint4 = 8 halfs):
// e-loop 16 -> 8 iters, half the exposure events, half the VMEM insts,
// same FLOPs/traffic. Regs ~78 < cap 84 at (256,3) (R8 precedent clean).

#define NTOK 16

typedef __attribute__((ext_vector_type(2))) _Float16 h2v;

__device__ __forceinline__ float fdot2f(unsigned int a, unsigned int b, float c) {
#if __has_builtin(__builtin_amdgcn_fdot2)
    return __builtin_amdgcn_fdot2(__builtin_bit_cast(h2v, a),
                                  __builtin_bit_cast(h2v, b), c, false);
#else
    h2v av = __builtin_bit_cast(h2v, a);
    h2v bv = __builtin_bit_cast(h2v, b);
    return fmaf((float)av[1], (float)bv[1],
           fmaf((float)av[0], (float)bv[0], c));
#endif
}

__device__ __forceinline__ unsigned int pk_f16(float a, float b) {
    const auto p = __builtin_amdgcn_cvt_pkrtz(a, b);   // __fp16x2
    return __builtin_bit_cast(unsigned int, p);
}

__device__ __forceinline__ float sigmoid_f(float z) {
    return 1.0f / (1.0f + __expf(-z));
}

// sum over each aligned 16-lane row via DPP row_ror (VALU-only)
__device__ __forceinline__ float row16_sum(float x) {
    x += __int_as_float(__builtin_amdgcn_update_dpp(
        0, __float_as_int(x), 0x121, 0xf, 0xf, false)); // row_ror:1
    x += __int_as_float(__builtin_amdgcn_update_dpp(
        0, __float_as_int(x), 0x122, 0xf, 0xf, false)); // row_ror:2
    x += __int_as_float(__builtin_amdgcn_update_dpp(
        0, __float_as_int(x), 0x124, 0xf, 0xf, false)); // row_ror:4
    x += __int_as_float(__builtin_amdgcn_update_dpp(
        0, __float_as_int(x), 0x128, 0xf, 0xf, false)); // row_ror:8
    return x;
}

// ---- prep: fold alpha*nw*w -> f16 wt[24][1024] (n-major) in d_ws ----
__global__ __launch_bounds__(256)
void prep_kernel(const float* __restrict__ nw,
                 const float* __restrict__ w,
                 const float* __restrict__ alpha,
                 unsigned short* __restrict__ wt)
{
    const int tid = blockIdx.x * 256 + threadIdx.x;   // 6144 threads
    const int flat = 4 * tid;                          // w is [k][n], flat=k*24+n
    const float4 w4 = *(const float4*)(w + flat);
    const float a0 = alpha[0], a1 = alpha[1], a2 = alpha[2];
    const float vals[4] = {w4.x, w4.y, w4.z, w4.w};
    #pragma unroll
    for (int c = 0; c < 4; ++c) {
        const int f = flat + c;
        const int k = f / 24;
        const int n = f - 24 * k;
        const float as = (n < 4) ? a0 : ((n < 8) ? a1 : a2);
        const unsigned int p = pk_f16(as * nw[k] * vals[c], 0.f);
        wt[n * 1024 + k] = (unsigned short)(p & 0xffffu);
    }
}

__global__ __launch_bounds__(256, 3)
void mhc_kernel(const float* __restrict__ h,
                const unsigned short* __restrict__ wt,
                const float* __restrict__ beta,
                float* __restrict__ out)
{
    const int tid  = threadIdx.x;
    const int lane = tid & 63;
    const int wv   = tid >> 6;     // wave id: owns tokens [4wv, 4wv+4)
    const int ksl  = lane & 15;    // k-slice lane
    const int ng   = lane >> 4;    // n-group (6 n's each)

    __shared__ unsigned int tile[NTOK * 512];  // f16 x-tile, 32KB
    __shared__ float Hpart[NTOK][28];          // [0:24) H, [24] r2
    __shared__ float smalls[NTOK][26];         // Hpre, Hpost, P

    const long tok0 = (long)blockIdx.x * NTOK;

    // ---- stage: 16 rows, f32 -> f16 pack, 64KB read -> 32KB LDS ----
    {
        const float* src = h + tok0 * 1024 + 4 * tid;
        #pragma unroll
        for (int i = 0; i < NTOK; ++i) {
            const float4 v = *(const float4*)(src + 1024 * i);
            uint2 u;
            u.x = pk_f16(v.x, v.y);
            u.y = pk_f16(v.z, v.w);
            *(uint2*)(tile + i * 512 + 2 * tid) = u;
        }
    }
    __syncthreads();

    // ---- phase A: 4 tokens/wave, b128 loads, 8 e-iters, fdot2 MACs ----
    const int t0 = 4 * wv;
    // uint4 view: tile row = 128 uint4; wt row = 128 uint4.
    // lane covers halfs [e*128 + 8*ksl, +8) -> uint4 index e*16 + ksl.
    const uint4* txp = (const uint4*)tile + t0 * 128 + ksl;
    const uint4* twp = (const uint4*)wt + (6 * ng) * 128 + ksl;

    float acc[4][6], r2[4];
    #pragma unroll
    for (int t = 0; t < 4; ++t) {
        r2[t] = 0.f;
        #pragma unroll
        for (int j = 0; j < 6; ++j) acc[t][j] = 0.f;
    }

    #pragma unroll 1
    for (int e = 0; e < 8; ++e) {
        uint4 xw[4];
        #pragma unroll
        for (int t = 0; t < 4; ++t) xw[t] = txp[t * 128 + e * 16];   // LDS b128
        uint4 wr[6];
        #pragma unroll
        for (int j = 0; j < 6; ++j) wr[j] = twp[j * 128 + e * 16];   // L2 b128

        #pragma unroll
        for (int j = 0; j < 6; ++j) {
            #pragma unroll
            for (int t = 0; t < 4; ++t) {
                float a = acc[t][j];
                a = fdot2f(xw[t].x, wr[j].x, a);
                a = fdot2f(xw[t].y, wr[j].y, a);
                a = fdot2f(xw[t].z, wr[j].z, a);
                a = fdot2f(xw[t].w, wr[j].w, a);
                acc[t][j] = a;
            }
        }
        #pragma unroll
        for (int t = 0; t < 4; ++t) {
            float r = r2[t];
            r = fdot2f(xw[t].x, xw[t].x, r);
            r = fdot2f(xw[t].y, xw[t].y, r);
            r = fdot2f(xw[t].z, xw[t].z, r);
            r = fdot2f(xw[t].w, xw[t].w, r);
            r2[t] = r;
        }
    }

    // ---- DPP reduce over ksl -> FINAL H for this wave's 4 tokens ----
    #pragma unroll
    for (int t = 0; t < 4; ++t) {
        #pragma unroll
        for (int j = 0; j < 6; ++j) acc[t][j] = row16_sum(acc[t][j]);
        r2[t] = row16_sum(r2[t]);
    }
    if (ksl == 0) {
        #pragma unroll
        for (int t = 0; t < 4; ++t) {
            #pragma unroll
            for (int j = 0; j < 6; ++j)
                Hpart[t0 + t][6 * ng + j] = acc[t][j];
            if (ng == 0) Hpart[t0 + t][24] = r2[t];
        }
    }
    __syncthreads();

    // ---- scalar phase: lanes 0..15, one token each (R2-proven) ----
    if (tid < NTOK) {
        const int t = tid;
        float Hp[24];
        #pragma unroll
        for (int q = 0; q < 24; ++q) Hp[q] = Hpart[t][q];
        const float r2v = Hpart[t][24];
        const float r_ = 1.0f / (sqrtf(r2v) * 0.03125f + 1e-6f);

        float Hpre[4], Hpost[4], K[16];
        #pragma unroll
        for (int n = 0; n < 4; ++n)
            Hpre[n] = sigmoid_f(fmaf(r_, Hp[n], beta[n]));
        #pragma unroll
        for (int n = 0; n < 4; ++n)
            Hpost[n] = 2.0f * sigmoid_f(fmaf(r_, Hp[4 + n], beta[4 + n]));
        #pragma unroll
        for (int q = 0; q < 16; ++q)
            K[q] = __expf(fmaf(r_, Hp[8 + q], beta[8 + q]));

        float u0=1.f,u1=1.f,u2=1.f,u3=1.f;
        float v0=1.f,v1=1.f,v2=1.f,v3=1.f;
        for (int itr = 0; itr < 10; ++itr) {
            u0 = 1.0f/(K[0]*v0  + K[1]*v1  + K[2]*v2  + K[3]*v3  + 1e-8f);
            u1 = 1.0f/(K[4]*v0  + K[5]*v1  + K[6]*v2  + K[7]*v3  + 1e-8f);
            u2 = 1.0f/(K[8]*v0  + K[9]*v1  + K[10]*v2 + K[11]*v3 + 1e-8f);
            u3 = 1.0f/(K[12]*v0 + K[13]*v1 + K[14]*v2 + K[15]*v3 + 1e-8f);
            v0 = 1.0f/(K[0]*u0  + K[4]*u1  + K[8]*u2  + K[12]*u3 + 1e-8f);
            v1 = 1.0f/(K[1]*u0  + K[5]*u1  + K[9]*u2  + K[13]*u3 + 1e-8f);
            v2 = 1.0f/(K[2]*u0  + K[6]*u1  + K[10]*u2 + K[14]*u3 + 1e-8f);
            v3 = 1.0f/(K[3]*u0  + K[7]*u1  + K[11]*u2 + K[15]*u3 + 1e-8f);
        }
        smalls[t][0] = Hpre[0];  smalls[t][1] = Hpre[1];
        smalls[t][2] = Hpre[2];  smalls[t][3] = Hpre[3];
        smalls[t][4] = Hpost[0]; smalls[t][5] = Hpost[1];
        smalls[t][6] = Hpost[2]; smalls[t][7] = Hpost[3];
        smalls[t][8]  = u0*K[0]*v0;   smalls[t][9]  = u0*K[1]*v1;
        smalls[t][10] = u0*K[2]*v2;   smalls[t][11] = u0*K[3]*v3;
        smalls[t][12] = u1*K[4]*v0;   smalls[t][13] = u1*K[5]*v1;
        smalls[t][14] = u1*K[6]*v2;   smalls[t][15] = u1*K[7]*v3;
        smalls[t][16] = u2*K[8]*v0;   smalls[t][17] = u2*K[9]*v1;
        smalls[t][18] = u2*K[10]*v2;  smalls[t][19] = u2*K[11]*v3;
        smalls[t][20] = u3*K[12]*v0;  smalls[t][21] = u3*K[13]*v1;
        smalls[t][22] = u3*K[14]*v2;  smalls[t][23] = u3*K[15]*v3;
    }
    __syncthreads();

    // ---- phase C: x from f16 tile (no global h re-read) ----
    const int gg = wv;   // n = gg, d = 4*lane..+3
    for (int it = 0; it < NTOK; ++it) {
        const uint2* tl = (const uint2*)tile + it * 256 + lane;
        float xm[4][4];
        #pragma unroll
        for (int m = 0; m < 4; ++m) {
            const uint2 u = tl[m * 64];
            const h2v p0 = __builtin_bit_cast(h2v, u.x);
            const h2v p1 = __builtin_bit_cast(h2v, u.y);
            xm[m][0] = (float)p0[0]; xm[m][1] = (float)p0[1];
            xm[m][2] = (float)p1[0]; xm[m][3] = (float)p1[1];
        }

        const float hp0 = smalls[it][0], hp1 = smalls[it][1];
        const float hp2 = smalls[it][2], hp3 = smalls[it][3];
        const float hpost = smalls[it][4 + gg];
        const float P0 = smalls[it][8 + 4*gg + 0];
        const float P1 = smalls[it][8 + 4*gg + 1];
        const float P2 = smalls[it][8 + 4*gg + 2];
        const float P3 = smalls[it][8 + 4*gg + 3];

        float4 o;
        #pragma unroll
        for (int c = 0; c < 4; ++c) {
            const float hpre = hp0*xm[0][c] + hp1*xm[1][c]
                             + hp2*xm[2][c] + hp3*xm[3][c];
            const float res  = P0*xm[0][c] + P1*xm[1][c]
                             + P2*xm[2][c] + P3*xm[3][c];
            ((float*)&o)[c] = fmaf(hpost, hpre, res);
        }
        *(float4*)(out + (tok0 + it) * 1024 + gg * 256 + 4 * lane) = o;
    }
}

extern "C" void kernel_launch(void* const* d_in, const int* in_sizes, int n_in,
                              void* d_out, int out_size, void* d_ws, size_t ws_size,
                              hipStream_t stream) {
    const float* h     = (const float*)d_in[0];
    const float* nw    = (const float*)d_in[1];
    const float* w     = (const float*)d_in[2];
    const float* alpha = (const float*)d_in[3];
    const float* beta  = (const float*)d_in[4];
    float* out = (float*)d_out;
    unsigned short* wt = (unsigned short*)d_ws;   // 24*1024*2B = 48KB

    prep_kernel<<<24, 256, 0, stream>>>(nw, w, alpha, wt);
    // 32768 tokens / 16 per block = 2048 blocks
    mhc_kernel<<<2048, 256, 0, stream>>>(h, wt, beta, out);
}